// Round 3
// baseline (347.456 us; speedup 1.0000x reference)
//
#include <hip/hip_runtime.h>
#include <hip/hip_fp16.h>
#include <stdint.h>

#define B_ 32
#define S_ 1024
#define DM 256
#define H_ 8
#define M_ (B_*S_)

typedef _Float16 f16;
typedef _Float16 f16x8 __attribute__((ext_vector_type(8)));
typedef _Float16 f16x4 __attribute__((ext_vector_type(4)));
typedef float f32x4 __attribute__((ext_vector_type(4)));

static __device__ __forceinline__ void gload16(const void* g, void* lds) {
  __builtin_amdgcn_global_load_lds(
      (const __attribute__((address_space(1))) void*)(uintptr_t)g,
      (__attribute__((address_space(3))) void*)(uintptr_t)lds, 16, 0, 0);
}

__global__ __launch_bounds__(256) void cvt_kernel(const float* __restrict__ in,
                                                  f16* __restrict__ out, int n4) {
  int i = blockIdx.x * blockDim.x + threadIdx.x;
  int stride = gridDim.x * blockDim.x;
  for (; i < n4; i += stride) {
    float4 v = reinterpret_cast<const float4*>(in)[i];
    f16x4 h = {(f16)v.x, (f16)v.y, (f16)v.z, (f16)v.w};
    reinterpret_cast<f16x4*>(out)[i] = h;
  }
}

__global__ __launch_bounds__(256) void pack_mask_kernel(const int* __restrict__ mask,
                                                        unsigned* __restrict__ pm, int nw) {
  int t = blockIdx.x * blockDim.x + threadIdx.x;
  if (t >= nw) return;
  const int* p = mask + (size_t)t * 32;
  unsigned bits = 0;
#pragma unroll
  for (int i = 0; i < 32; ++i) bits |= (p[i] != 0 ? 1u : 0u) << i;
  pm[t] = bits;
}

// C = A @ W^T + b ; A[M][256] f16, W[(768|256)][256] f16. 128x128 tile, 4 waves.
__global__ __launch_bounds__(256) void qkv_gemm_kernel(
    const f16* __restrict__ xh, const f16* __restrict__ wh,
    const float* __restrict__ bq, const float* __restrict__ bk, const float* __restrict__ bv,
    f16* __restrict__ qh, f16* __restrict__ kh, f16* __restrict__ vth) {
  __shared__ __align__(16) f16 Al[128 * 32];
  __shared__ __align__(16) f16 Bl[128 * 32];
  const int tid = threadIdx.x;
  const int w = tid >> 6, l = tid & 63;
  const int mt = blockIdx.x / 6, nt = blockIdx.x % 6;
  const int mbase = mt * 128, nbase = nt * 128;
  const int wm = w >> 1, wn = w & 1;
  const int lg = l >> 4, lr = l & 15;
  f32x4 acc[4][4] = {};
  for (int ks = 0; ks < 8; ++ks) {
    __syncthreads();
#pragma unroll
    for (int j = 0; j < 2; ++j) {
      int c = (j * 4 + w) * 64 + l;
      gload16(xh + (size_t)(mbase + (c >> 2)) * 256 + ks * 32 + (c & 3) * 8,
              (char*)Al + (j * 4 + w) * 1024);
      gload16(wh + (size_t)(nbase + (c >> 2)) * 256 + ks * 32 + (c & 3) * 8,
              (char*)Bl + (j * 4 + w) * 1024);
    }
    __syncthreads();
    f16x8 af[4], bf[4];
#pragma unroll
    for (int i = 0; i < 4; ++i)
      af[i] = *(const f16x8*)((const char*)Al + (wm * 64 + i * 16 + lr) * 64 + lg * 16);
#pragma unroll
    for (int i = 0; i < 4; ++i)
      bf[i] = *(const f16x8*)((const char*)Bl + (wn * 64 + i * 16 + lr) * 64 + lg * 16);
#pragma unroll
    for (int mi = 0; mi < 4; ++mi)
#pragma unroll
      for (int ni = 0; ni < 4; ++ni)
        acc[mi][ni] = __builtin_amdgcn_mfma_f32_16x16x32_f16(af[mi], bf[ni], acc[mi][ni], 0, 0, 0);
  }
  const int proj = nt >> 1;
  const float* bias = proj == 0 ? bq : (proj == 1 ? bk : bv);
#pragma unroll
  for (int mi = 0; mi < 4; ++mi) {
#pragma unroll
    for (int ni = 0; ni < 4; ++ni) {
      int n = nbase + wn * 64 + ni * 16 + lr;
      float bb = bias[n & 255];
#pragma unroll
      for (int r = 0; r < 4; ++r) {
        int m = mbase + wm * 64 + mi * 16 + lg * 4 + r;
        f16 hv = (f16)(acc[mi][ni][r] + bb);
        int b = m >> 10, s = m & 1023;
        int hh = (n >> 5) & 7, d = n & 31;
        int bh = b * 8 + hh;
        if (proj == 0)      qh[((size_t)bh * 1024 + s) * 32 + d] = hv;
        else if (proj == 1) kh[((size_t)bh * 1024 + s) * 32 + d] = hv;
        else                vth[((size_t)bh * 32 + d) * 1024 + s] = hv;
      }
    }
  }
}

// Flash attention: grid = bh*16 + qtile, 4 waves x 16 q-rows, KV tiles of 64.
__global__ __launch_bounds__(256) void attn_kernel(
    const f16* __restrict__ qh, const f16* __restrict__ kh, const f16* __restrict__ vth,
    const unsigned* __restrict__ pm, f16* __restrict__ attnh) {
  __shared__ __align__(16) f16 Kl[64 * 32];
  __shared__ __align__(16) f16 Vtl[32 * 64];
  __shared__ __align__(16) f16 Pl[4][16 * 64];
  const int tid = threadIdx.x;
  const int w = tid >> 6, l = tid & 63;
  const int bh = blockIdx.x >> 4, qt = blockIdx.x & 15;
  const int qbase = qt * 64;
  const int lg = l >> 4, lr = l & 15;
  const float scale = 0.17677669529663687f; // 1/sqrt(32)

  f16x8 qf = *(const f16x8*)(qh + ((size_t)bh * 1024 + qbase + w * 16 + lr) * 32 + lg * 8);
  float mrun[4], lrun[4];
#pragma unroll
  for (int r = 0; r < 4; ++r) { mrun[r] = -__builtin_inff(); lrun[r] = 0.f; }
  f32x4 oacc[2] = {};
  const f32x4 zero = {};

  for (int t = 0; t < 16; ++t) {
    const int kvb = t * 64;
    __syncthreads();
    {
      int c = w * 64 + l;
      gload16(kh + ((size_t)bh * 1024 + kvb + (c >> 2)) * 32 + (c & 3) * 8,
              (char*)Kl + w * 1024);
      int cd = c ^ ((c >> 3) & 7); // pre-swizzle global source; LDS dest stays linear
      gload16(vth + ((size_t)bh * 32 + (c >> 3)) * 1024 + kvb + (cd & 7) * 8,
              (char*)Vtl + w * 1024);
    }
    __syncthreads();

    f32x4 sc[4];
#pragma unroll
    for (int kt = 0; kt < 4; ++kt) {
      f16x8 kf = *(const f16x8*)((const char*)Kl + (kt * 16 + lr) * 64 + lg * 16);
      sc[kt] = __builtin_amdgcn_mfma_f32_16x16x32_f16(qf, kf, zero, 0, 0, 0);
    }
    // scale + mask (packed bits)
#pragma unroll
    for (int r = 0; r < 4; ++r) {
      int qg = qbase + w * 16 + lg * 4 + r;
#pragma unroll
      for (int wi = 0; wi < 2; ++wi) {
        unsigned word = pm[qg * 32 + t * 2 + wi];
#pragma unroll
        for (int k2 = 0; k2 < 2; ++k2) {
          int kt = wi * 2 + k2;
          float v = sc[kt][r] * scale;
          unsigned bit = (word >> (k2 * 16 + lr)) & 1u;
          sc[kt][r] = bit ? v : -1e9f;
        }
      }
    }
    // online softmax (rows live in 16-lane groups)
    float pr[4][4];
#pragma unroll
    for (int r = 0; r < 4; ++r) {
      float rm = fmaxf(fmaxf(sc[0][r], sc[1][r]), fmaxf(sc[2][r], sc[3][r]));
#pragma unroll
      for (int off = 8; off >= 1; off >>= 1) rm = fmaxf(rm, __shfl_xor(rm, off));
      float mnew = fmaxf(mrun[r], rm);
      float alpha = __expf(mrun[r] - mnew);
      mrun[r] = mnew;
      float rs = 0.f;
#pragma unroll
      for (int kt = 0; kt < 4; ++kt) {
        float p = __expf(sc[kt][r] - mnew);
        pr[kt][r] = p;
        rs += p;
      }
#pragma unroll
      for (int off = 8; off >= 1; off >>= 1) rs += __shfl_xor(rs, off);
      lrun[r] = lrun[r] * alpha + rs;
      oacc[0][r] *= alpha;
      oacc[1][r] *= alpha;
    }
    // P -> LDS (XOR-swizzled), per-wave private region
#pragma unroll
    for (int kt = 0; kt < 4; ++kt) {
      int col = kt * 16 + lr;
      int cc = col >> 3;
#pragma unroll
      for (int r = 0; r < 4; ++r) {
        int row = lg * 4 + r;
        *((f16*)((char*)Pl[w] + row * 128 + ((cc ^ (row & 7)) << 4) + (col & 7) * 2)) =
            (f16)pr[kt][r];
      }
    }
    // PV
#pragma unroll
    for (int ss = 0; ss < 2; ++ss) {
      f16x8 pa = *(const f16x8*)((const char*)Pl[w] + lr * 128 + (((ss * 4 + lg) ^ (lr & 7)) << 4));
#pragma unroll
      for (int dt = 0; dt < 2; ++dt) {
        int vrow = dt * 16 + lr;
        f16x8 vf = *(const f16x8*)((const char*)Vtl + vrow * 128 + (((ss * 4 + lg) ^ (vrow & 7)) << 4));
        oacc[dt] = __builtin_amdgcn_mfma_f32_16x16x32_f16(pa, vf, oacc[dt], 0, 0, 0);
      }
    }
  }
  const int b = bh >> 3, hh = bh & 7;
#pragma unroll
  for (int r = 0; r < 4; ++r) {
    float inv = 1.f / lrun[r];
    int q = qbase + w * 16 + lg * 4 + r;
    size_t rowoff = ((size_t)b * 1024 + q) * 256 + hh * 32;
    attnh[rowoff + lr]      = (f16)(oacc[0][r] * inv);
    attnh[rowoff + 16 + lr] = (f16)(oacc[1][r] * inv);
  }
}

__global__ __launch_bounds__(256) void out_gemm_kernel(
    const f16* __restrict__ ah, const f16* __restrict__ wh,
    const float* __restrict__ bo, float* __restrict__ out) {
  __shared__ __align__(16) f16 Al[128 * 32];
  __shared__ __align__(16) f16 Bl[128 * 32];
  const int tid = threadIdx.x;
  const int w = tid >> 6, l = tid & 63;
  const int mt = blockIdx.x >> 1, nt = blockIdx.x & 1;
  const int mbase = mt * 128, nbase = nt * 128;
  const int wm = w >> 1, wn = w & 1;
  const int lg = l >> 4, lr = l & 15;
  f32x4 acc[4][4] = {};
  for (int ks = 0; ks < 8; ++ks) {
    __syncthreads();
#pragma unroll
    for (int j = 0; j < 2; ++j) {
      int c = (j * 4 + w) * 64 + l;
      gload16(ah + (size_t)(mbase + (c >> 2)) * 256 + ks * 32 + (c & 3) * 8,
              (char*)Al + (j * 4 + w) * 1024);
      gload16(wh + (size_t)(nbase + (c >> 2)) * 256 + ks * 32 + (c & 3) * 8,
              (char*)Bl + (j * 4 + w) * 1024);
    }
    __syncthreads();
    f16x8 af[4], bf[4];
#pragma unroll
    for (int i = 0; i < 4; ++i)
      af[i] = *(const f16x8*)((const char*)Al + (wm * 64 + i * 16 + lr) * 64 + lg * 16);
#pragma unroll
    for (int i = 0; i < 4; ++i)
      bf[i] = *(const f16x8*)((const char*)Bl + (wn * 64 + i * 16 + lr) * 64 + lg * 16);
#pragma unroll
    for (int mi = 0; mi < 4; ++mi)
#pragma unroll
      for (int ni = 0; ni < 4; ++ni)
        acc[mi][ni] = __builtin_amdgcn_mfma_f32_16x16x32_f16(af[mi], bf[ni], acc[mi][ni], 0, 0, 0);
  }
#pragma unroll
  for (int mi = 0; mi < 4; ++mi) {
#pragma unroll
    for (int ni = 0; ni < 4; ++ni) {
      int n = nbase + wn * 64 + ni * 16 + lr;
      float bb = bo[n];
#pragma unroll
      for (int r = 0; r < 4; ++r) {
        int m = mbase + wm * 64 + mi * 16 + lg * 4 + r;
        out[(size_t)m * 256 + n] = acc[mi][ni][r] + bb;
      }
    }
  }
}

extern "C" void kernel_launch(void* const* d_in, const int* in_sizes, int n_in,
                              void* d_out, int out_size, void* d_ws, size_t ws_size,
                              hipStream_t stream) {
  const float* x  = (const float*)d_in[0];
  const int* mask = (const int*)d_in[1];
  const float* Wq = (const float*)d_in[2];
  const float* bq = (const float*)d_in[3];
  const float* Wk = (const float*)d_in[4];
  const float* bk = (const float*)d_in[5];
  const float* Wv = (const float*)d_in[6];
  const float* bv = (const float*)d_in[7];
  const float* Wo = (const float*)d_in[8];
  const float* bo = (const float*)d_in[9];
  float* out = (float*)d_out;
  char* ws = (char*)d_ws;

  f16* xh    = (f16*)(ws);                 // 16 MB (aliased by attnh after QKV GEMM)
  f16* attnh = (f16*)(ws);
  f16* qh    = (f16*)(ws + 16777216);
  f16* kh    = (f16*)(ws + 33554432);
  f16* vth   = (f16*)(ws + 50331648);      // V transposed [bh][32][1024]
  f16* wqkvh = (f16*)(ws + 67108864);      // [768][256]
  f16* woh   = (f16*)(ws + 67502080);      // [256][256]
  unsigned* pm = (unsigned*)(ws + 67633152); // [1024][32] mask bits

  cvt_kernel<<<2048, 256, 0, stream>>>(x, xh, (B_*S_*DM) / 4);
  cvt_kernel<<<64, 256, 0, stream>>>(Wq, wqkvh, 16384);
  cvt_kernel<<<64, 256, 0, stream>>>(Wk, wqkvh + 65536, 16384);
  cvt_kernel<<<64, 256, 0, stream>>>(Wv, wqkvh + 131072, 16384);
  cvt_kernel<<<64, 256, 0, stream>>>(Wo, woh, 16384);
  pack_mask_kernel<<<128, 256, 0, stream>>>(mask, pm, 32768);
  qkv_gemm_kernel<<<1536, 256, 0, stream>>>(xh, wqkvh, bq, bk, bv, qh, kh, vth);
  attn_kernel<<<4096, 256, 0, stream>>>(qh, kh, vth, pm, attnh);
  out_gemm_kernel<<<512, 256, 0, stream>>>(attnh, woh, bo, out);
}

// Round 6
// 309.341 us; speedup vs baseline: 1.1232x; 1.1232x over previous
//
#include <hip/hip_runtime.h>
#include <hip/hip_fp16.h>
#include <stdint.h>

#define B_ 32
#define S_ 1024
#define DM 256
#define H_ 8

typedef _Float16 f16;
typedef _Float16 f16x8 __attribute__((ext_vector_type(8)));
typedef _Float16 f16x4 __attribute__((ext_vector_type(4)));
typedef float f32x4 __attribute__((ext_vector_type(4)));

static __device__ __forceinline__ void gload16(const void* g, void* lds) {
  __builtin_amdgcn_global_load_lds(
      (const __attribute__((address_space(1))) void*)(uintptr_t)g,
      (__attribute__((address_space(3))) void*)(uintptr_t)lds, 16, 0, 0);
}
static __device__ __forceinline__ float ex2(float x) {
  float r; asm("v_exp_f32 %0, %1" : "=v"(r) : "v"(x)); return r;
}
static __device__ __forceinline__ unsigned pkrtz(float a, float b) {
  unsigned r; asm("v_cvt_pkrtz_f16_f32 %0, %1, %2" : "=v"(r) : "v"(a), "v"(b)); return r;
}
static __device__ __forceinline__ unsigned pkmul(unsigned a, unsigned b) {
  unsigned r; asm("v_pk_mul_f16 %0, %1, %2" : "=v"(r) : "v"(a), "v"(b)); return r;
}

__global__ __launch_bounds__(256) void cvt_kernel(const float* __restrict__ in,
                                                  f16* __restrict__ out, int n4) {
  int i = blockIdx.x * blockDim.x + threadIdx.x;
  int stride = gridDim.x * blockDim.x;
  for (; i < n4; i += stride) {
    float4 v = reinterpret_cast<const float4*>(in)[i];
    f16x4 h = {(f16)v.x, (f16)v.y, (f16)v.z, (f16)v.w};
    reinterpret_cast<f16x4*>(out)[i] = h;
  }
}

// mask int -> packed f16-pair multiplicand table [1024][512] u32
__global__ __launch_bounds__(256) void expand_mask_kernel(const int* __restrict__ mask,
                                                          unsigned* __restrict__ pmx, int n) {
  int t = blockIdx.x * blockDim.x + threadIdx.x;
  if (t >= n) return;
  int2 mm = reinterpret_cast<const int2*>(mask)[t];
  pmx[t] = (mm.x ? 0x3C00u : 0u) | (mm.y ? 0x3C000000u : 0u);
}

// C = A @ W^T + b ; Q output pre-scaled by log2(e)/sqrt(32). 128x128 tile, 4 waves.
__global__ __launch_bounds__(256) void qkv_gemm_kernel(
    const f16* __restrict__ xh, const f16* __restrict__ wh,
    const float* __restrict__ bq, const float* __restrict__ bk, const float* __restrict__ bv,
    f16* __restrict__ qh, f16* __restrict__ kh, f16* __restrict__ vth) {
  __shared__ __align__(16) f16 Al[128 * 32];
  __shared__ __align__(16) f16 Bl[128 * 32];
  const int tid = threadIdx.x;
  const int w = tid >> 6, l = tid & 63;
  const int mt = blockIdx.x / 6, nt = blockIdx.x % 6;
  const int mbase = mt * 128, nbase = nt * 128;
  const int wm = w >> 1, wn = w & 1;
  const int lg = l >> 4, lr = l & 15;
  f32x4 acc[4][4] = {};
  for (int ks = 0; ks < 8; ++ks) {
    __syncthreads();
#pragma unroll
    for (int j = 0; j < 2; ++j) {
      int c = (j * 4 + w) * 64 + l;
      gload16(xh + (size_t)(mbase + (c >> 2)) * 256 + ks * 32 + (c & 3) * 8,
              (char*)Al + (j * 4 + w) * 1024);
      gload16(wh + (size_t)(nbase + (c >> 2)) * 256 + ks * 32 + (c & 3) * 8,
              (char*)Bl + (j * 4 + w) * 1024);
    }
    __syncthreads();
    f16x8 af[4], bf[4];
#pragma unroll
    for (int i = 0; i < 4; ++i)
      af[i] = *(const f16x8*)((const char*)Al + (wm * 64 + i * 16 + lr) * 64 + lg * 16);
#pragma unroll
    for (int i = 0; i < 4; ++i)
      bf[i] = *(const f16x8*)((const char*)Bl + (wn * 64 + i * 16 + lr) * 64 + lg * 16);
#pragma unroll
    for (int mi = 0; mi < 4; ++mi)
#pragma unroll
      for (int ni = 0; ni < 4; ++ni)
        acc[mi][ni] = __builtin_amdgcn_mfma_f32_16x16x32_f16(af[mi], bf[ni], acc[mi][ni], 0, 0, 0);
  }
  const int proj = nt >> 1;
  const float* bias = proj == 0 ? bq : (proj == 1 ? bk : bv);
  const float qsc = 0.25504182524668425f; // log2(e)/sqrt(32)
#pragma unroll
  for (int mi = 0; mi < 4; ++mi) {
#pragma unroll
    for (int ni = 0; ni < 4; ++ni) {
      int n = nbase + wn * 64 + ni * 16 + lr;
      float bb = bias[n & 255];
#pragma unroll
      for (int r = 0; r < 4; ++r) {
        int m = mbase + wm * 64 + mi * 16 + lg * 4 + r;
        float val = acc[mi][ni][r] + bb;
        if (proj == 0) val *= qsc;
        f16 hv = (f16)val;
        int b = m >> 10, s = m & 1023;
        int hh = (n >> 5) & 7, d = n & 31;
        int bh = b * 8 + hh;
        if (proj == 0)      qh[((size_t)bh * 1024 + s) * 32 + d] = hv;
        else if (proj == 1) kh[((size_t)bh * 1024 + s) * 32 + d] = hv;
        else                vth[((size_t)bh * 32 + d) * 1024 + s] = hv;
      }
    }
  }
}

// Flash attention v2: swapped QK^T, exp2 domain, post-exp packed mask,
// l via ones-MFMA, deferred rescale, double-buffered staging.
__global__ __launch_bounds__(256) void attn_kernel(
    const f16* __restrict__ qh, const f16* __restrict__ kh, const f16* __restrict__ vth,
    const unsigned* __restrict__ pmx, f16* __restrict__ attnh) {
  __shared__ __align__(16) f16 Kl[2][64 * 32];
  __shared__ __align__(16) f16 Vtl[2][32 * 64];
  __shared__ __align__(16) f16 Pl[4][16 * 64];
  const int tid = threadIdx.x;
  const int w = tid >> 6, l = tid & 63;
  const int bh = blockIdx.x >> 4, qt = blockIdx.x & 15;
  const int qbase = qt * 64;
  const int lg = l >> 4, lr = l & 15;
  const int q = qbase + w * 16 + lr;   // this lane's q-row (col side of swapped QK)

  f16x8 qf = *(const f16x8*)(qh + ((size_t)bh * 1024 + q) * 32 + lg * 8);
  const unsigned* mrow = pmx + (size_t)q * 512;

  float mrun = -1e30f;
  f32x4 oacc[2] = {};
  f32x4 lacc = {};
  const f32x4 zero = {};
  f16x8 ones;
#pragma unroll
  for (int i = 0; i < 8; ++i) ones[i] = (f16)1.0f;

  // staging coords: K row=tid>>2 chunk=tid&3 ; Vt dv=tid>>3, logical slot s=(tid&7)^((tid>>3)&7)
  const f16* kgbase = kh + ((size_t)bh * 1024 + (tid >> 2)) * 32 + (tid & 3) * 8;
  const f16* vgbase = vth + ((size_t)bh * 32 + (tid >> 3)) * 1024 + ((tid & 7) ^ ((tid >> 3) & 7)) * 8;

  uint2 mc[4], mn[4];
  // prologue: mask(0) first, then STAGE(0)  (keeps vmcnt accounting uniform)
#pragma unroll
  for (int k = 0; k < 4; ++k) mc[k] = *(const uint2*)(mrow + 0 * 32 + k * 8 + lg * 2);
  gload16(kgbase, (char*)Kl[0] + tid * 16);
  gload16(vgbase, (char*)Vtl[0] + tid * 16);

  for (int t = 0; t < 16; ++t) {
    asm volatile("" ::: "memory");          // pin prev-tile LDS reads above barrier
    __builtin_amdgcn_s_barrier();           // all waves done reading prev buffers
    const int nxt = t + 1;
    if (nxt < 16) {
#pragma unroll
      for (int k = 0; k < 4; ++k) mn[k] = *(const uint2*)(mrow + nxt * 32 + k * 8 + lg * 2);
      const int nb = nxt & 1;
      gload16(kgbase + (size_t)nxt * 64 * 32, (char*)Kl[nb] + tid * 16);
      gload16(vgbase + (size_t)nxt * 64, (char*)Vtl[nb] + tid * 16);
      asm volatile("s_waitcnt vmcnt(6)" ::: "memory");   // tile t staging arrived
    } else {
      asm volatile("s_waitcnt vmcnt(0)" ::: "memory");
    }
    __builtin_amdgcn_s_barrier();           // every wave's staging arrived

    const char* kbuf = (const char*)Kl[t & 1];
    const char* vbuf = (const char*)Vtl[t & 1];

    // QK^T swapped: D[row=kv_local][col=q]
    f32x4 sc[4];
#pragma unroll
    for (int kt = 0; kt < 4; ++kt) {
      f16x8 kf = *(const f16x8*)(kbuf + (kt * 16 + lr) * 64 + lg * 16);
      sc[kt] = __builtin_amdgcn_mfma_f32_16x16x32_f16(kf, qf, zero, 0, 0, 0);
    }
    // tile max over raw scores (upper bound of masked max — safe for softmax)
    float t0 = fmaxf(fmaxf(sc[0][0], sc[0][1]), fmaxf(sc[0][2], sc[0][3]));
    float t1 = fmaxf(fmaxf(sc[1][0], sc[1][1]), fmaxf(sc[1][2], sc[1][3]));
    float t2 = fmaxf(fmaxf(sc[2][0], sc[2][1]), fmaxf(sc[2][2], sc[2][3]));
    float t3 = fmaxf(fmaxf(sc[3][0], sc[3][1]), fmaxf(sc[3][2], sc[3][3]));
    float pmax = fmaxf(fmaxf(t0, t1), fmaxf(t2, t3));
    pmax = fmaxf(pmax, __shfl_xor(pmax, 16));
    pmax = fmaxf(pmax, __shfl_xor(pmax, 32));
    // deferred rescale: only when max grows by >8 (log2 domain; p bounded by 256)
    if (__any(pmax > mrun + 8.0f)) {
      float mnew = fmaxf(mrun, pmax);
      float alpha = ex2(mrun - mnew);
      mrun = mnew;
#pragma unroll
      for (int r = 0; r < 4; ++r) {
        float ar = __shfl(alpha, (l & 48) | (lg * 4 + r), 64);
        oacc[0][r] *= ar;
        oacc[1][r] *= ar;
        lacc[r] *= ar;
      }
    }
    // p = exp2(sc - m), pack to f16 pairs, apply mask, write P (XOR-swizzled)
    char* pbuf = (char*)Pl[w];
#pragma unroll
    for (int kt = 0; kt < 4; ++kt) {
      float p0 = ex2(sc[kt][0] - mrun);
      float p1 = ex2(sc[kt][1] - mrun);
      float p2 = ex2(sc[kt][2] - mrun);
      float p3 = ex2(sc[kt][3] - mrun);
      unsigned lo = pkmul(pkrtz(p0, p1), mc[kt].x);
      unsigned hi = pkmul(pkrtz(p2, p3), mc[kt].y);
      *(uint64_t*)(pbuf + lr * 128 + ((kt * 32 + lg * 8) ^ ((lr & 7) << 4))) =
          (uint64_t)lo | ((uint64_t)hi << 32);
    }
    // PV + l accumulation (ones-MFMA gives row sums in acc layout)
#pragma unroll
    for (int ss = 0; ss < 2; ++ss) {
      f16x8 pa = *(const f16x8*)(pbuf + lr * 128 + ((ss * 64 + lg * 16) ^ ((lr & 7) << 4)));
      lacc = __builtin_amdgcn_mfma_f32_16x16x32_f16(pa, ones, lacc, 0, 0, 0);
#pragma unroll
      for (int dt = 0; dt < 2; ++dt) {
        int vr = dt * 16 + lr;
        f16x8 vf = *(const f16x8*)(vbuf + vr * 128 + ((ss * 64 + lg * 16) ^ ((lr & 7) << 4)));
        oacc[dt] = __builtin_amdgcn_mfma_f32_16x16x32_f16(pa, vf, oacc[dt], 0, 0, 0);
      }
    }
#pragma unroll
    for (int k = 0; k < 4; ++k) mc[k] = mn[k];
  }

  const int b = bh >> 3, hh = bh & 7;
#pragma unroll
  for (int r = 0; r < 4; ++r) {
    float inv = 1.0f / lacc[r];
    int qrow = qbase + w * 16 + lg * 4 + r;
    size_t rowoff = ((size_t)b * 1024 + qrow) * 256 + hh * 32;
    attnh[rowoff + lr]      = (f16)(oacc[0][r] * inv);
    attnh[rowoff + 16 + lr] = (f16)(oacc[1][r] * inv);
  }
}

__global__ __launch_bounds__(256) void out_gemm_kernel(
    const f16* __restrict__ ah, const f16* __restrict__ wh,
    const float* __restrict__ bo, float* __restrict__ out) {
  __shared__ __align__(16) f16 Al[128 * 32];
  __shared__ __align__(16) f16 Bl[128 * 32];
  const int tid = threadIdx.x;
  const int w = tid >> 6, l = tid & 63;
  const int mt = blockIdx.x >> 1, nt = blockIdx.x & 1;
  const int mbase = mt * 128, nbase = nt * 128;
  const int wm = w >> 1, wn = w & 1;
  const int lg = l >> 4, lr = l & 15;
  f32x4 acc[4][4] = {};
  for (int ks = 0; ks < 8; ++ks) {
    __syncthreads();
#pragma unroll
    for (int j = 0; j < 2; ++j) {
      int c = (j * 4 + w) * 64 + l;
      gload16(ah + (size_t)(mbase + (c >> 2)) * 256 + ks * 32 + (c & 3) * 8,
              (char*)Al + (j * 4 + w) * 1024);
      gload16(wh + (size_t)(nbase + (c >> 2)) * 256 + ks * 32 + (c & 3) * 8,
              (char*)Bl + (j * 4 + w) * 1024);
    }
    __syncthreads();
    f16x8 af[4], bf[4];
#pragma unroll
    for (int i = 0; i < 4; ++i)
      af[i] = *(const f16x8*)((const char*)Al + (wm * 64 + i * 16 + lr) * 64 + lg * 16);
#pragma unroll
    for (int i = 0; i < 4; ++i)
      bf[i] = *(const f16x8*)((const char*)Bl + (wn * 64 + i * 16 + lr) * 64 + lg * 16);
#pragma unroll
    for (int mi = 0; mi < 4; ++mi)
#pragma unroll
      for (int ni = 0; ni < 4; ++ni)
        acc[mi][ni] = __builtin_amdgcn_mfma_f32_16x16x32_f16(af[mi], bf[ni], acc[mi][ni], 0, 0, 0);
  }
#pragma unroll
  for (int mi = 0; mi < 4; ++mi) {
#pragma unroll
    for (int ni = 0; ni < 4; ++ni) {
      int n = nbase + wn * 64 + ni * 16 + lr;
      float bb = bo[n];
#pragma unroll
      for (int r = 0; r < 4; ++r) {
        int m = mbase + wm * 64 + mi * 16 + lg * 4 + r;
        out[(size_t)m * 256 + n] = acc[mi][ni][r] + bb;
      }
    }
  }
}

extern "C" void kernel_launch(void* const* d_in, const int* in_sizes, int n_in,
                              void* d_out, int out_size, void* d_ws, size_t ws_size,
                              hipStream_t stream) {
  const float* x  = (const float*)d_in[0];
  const int* mask = (const int*)d_in[1];
  const float* Wq = (const float*)d_in[2];
  const float* bq = (const float*)d_in[3];
  const float* Wk = (const float*)d_in[4];
  const float* bk = (const float*)d_in[5];
  const float* Wv = (const float*)d_in[6];
  const float* bv = (const float*)d_in[7];
  const float* Wo = (const float*)d_in[8];
  const float* bo = (const float*)d_in[9];
  float* out = (float*)d_out;
  char* ws = (char*)d_ws;

  f16* xh    = (f16*)(ws);                 // 16 MB (aliased by attnh after QKV GEMM)
  f16* attnh = (f16*)(ws);
  f16* qh    = (f16*)(ws + 16777216);
  f16* kh    = (f16*)(ws + 33554432);
  f16* vth   = (f16*)(ws + 50331648);      // V transposed [bh][32][1024]
  f16* wqkvh = (f16*)(ws + 67108864);      // [768][256]
  f16* woh   = (f16*)(ws + 67502080);      // [256][256]
  unsigned* pmx = (unsigned*)(ws + 67633152); // [1024][512] f16-pair mask table (2 MB)

  cvt_kernel<<<2048, 256, 0, stream>>>(x, xh, (B_*S_*DM) / 4);
  cvt_kernel<<<64, 256, 0, stream>>>(Wq, wqkvh, 16384);
  cvt_kernel<<<64, 256, 0, stream>>>(Wk, wqkvh + 65536, 16384);
  cvt_kernel<<<64, 256, 0, stream>>>(Wv, wqkvh + 131072, 16384);
  cvt_kernel<<<64, 256, 0, stream>>>(Wo, woh, 16384);
  expand_mask_kernel<<<2048, 256, 0, stream>>>(mask, pmx, 1024 * 512);
  qkv_gemm_kernel<<<1536, 256, 0, stream>>>(xh, wqkvh, bq, bk, bv, qh, kh, vth);
  attn_kernel<<<4096, 256, 0, stream>>>(qh, kh, vth, pmx, attnh);
  out_gemm_kernel<<<512, 256, 0, stream>>>(attnh, woh, bo, out);
}

// Round 11
// 302.492 us; speedup vs baseline: 1.1486x; 1.0226x over previous
//
#include <hip/hip_runtime.h>
#include <hip/hip_fp16.h>
#include <stdint.h>

#define B_ 32
#define S_ 1024
#define DM 256
#define H_ 8

typedef _Float16 f16;
typedef _Float16 f16x8 __attribute__((ext_vector_type(8)));
typedef _Float16 f16x4 __attribute__((ext_vector_type(4)));
typedef float f32x4 __attribute__((ext_vector_type(4)));

static __device__ __forceinline__ void gload16(const void* g, void* lds) {
  __builtin_amdgcn_global_load_lds(
      (const __attribute__((address_space(1))) void*)(uintptr_t)g,
      (__attribute__((address_space(3))) void*)(uintptr_t)lds, 16, 0, 0);
}
static __device__ __forceinline__ float ex2(float x) {
  float r; asm("v_exp_f32 %0, %1" : "=v"(r) : "v"(x)); return r;
}
static __device__ __forceinline__ unsigned pkrtz(float a, float b) {
  unsigned r; asm("v_cvt_pkrtz_f16_f32 %0, %1, %2" : "=v"(r) : "v"(a), "v"(b)); return r;
}
static __device__ __forceinline__ unsigned pkmul(unsigned a, unsigned b) {
  unsigned r; asm("v_pk_mul_f16 %0, %1, %2" : "=v"(r) : "v"(a), "v"(b)); return r;
}

// Merged prep: x->f16, 4 weights->f16 (contiguous dst), mask->packed f16-pair table.
__global__ __launch_bounds__(256) void prep_kernel(
    const float* __restrict__ x,
    const float* __restrict__ Wq, const float* __restrict__ Wk,
    const float* __restrict__ Wv, const float* __restrict__ Wo,
    const int* __restrict__ mask,
    f16* __restrict__ xh, f16* __restrict__ wh, unsigned* __restrict__ pmx) {
  int idx = blockIdx.x * 256 + threadIdx.x;
  if (idx < 2097152) {
    float4 v = reinterpret_cast<const float4*>(x)[idx];
    f16x4 h = {(f16)v.x, (f16)v.y, (f16)v.z, (f16)v.w};
    reinterpret_cast<f16x4*>(xh)[idx] = h;
  } else if (idx < 2097152 + 65536) {
    int j = idx - 2097152;
    const float* src = j < 16384 ? Wq : j < 32768 ? Wk : j < 49152 ? Wv : Wo;
    float4 v = reinterpret_cast<const float4*>(src)[j & 16383];
    f16x4 h = {(f16)v.x, (f16)v.y, (f16)v.z, (f16)v.w};
    reinterpret_cast<f16x4*>(wh)[j] = h;
  } else {
    int j = idx - (2097152 + 65536);
    int2 mm = reinterpret_cast<const int2*>(mask)[j];
    pmx[j] = (mm.x ? 0x3C00u : 0u) | (mm.y ? 0x3C000000u : 0u);
  }
}

// C = A @ W^T + b ; Q output pre-scaled by log2(e)/sqrt(32). 128x128 tile, 4 waves.
__global__ __launch_bounds__(256) void qkv_gemm_kernel(
    const f16* __restrict__ xh, const f16* __restrict__ wh,
    const float* __restrict__ bq, const float* __restrict__ bk, const float* __restrict__ bv,
    f16* __restrict__ qh, f16* __restrict__ kh, f16* __restrict__ vth) {
  __shared__ __align__(16) f16 Al[128 * 32];
  __shared__ __align__(16) f16 Bl[128 * 32];
  const int tid = threadIdx.x;
  const int w = tid >> 6, l = tid & 63;
  const int mt = blockIdx.x / 6, nt = blockIdx.x % 6;
  const int mbase = mt * 128, nbase = nt * 128;
  const int wm = w >> 1, wn = w & 1;
  const int lg = l >> 4, lr = l & 15;
  f32x4 acc[4][4] = {};
  for (int ks = 0; ks < 8; ++ks) {
    __syncthreads();
#pragma unroll
    for (int j = 0; j < 2; ++j) {
      int c = (j * 4 + w) * 64 + l;
      gload16(xh + (size_t)(mbase + (c >> 2)) * 256 + ks * 32 + (c & 3) * 8,
              (char*)Al + (j * 4 + w) * 1024);
      gload16(wh + (size_t)(nbase + (c >> 2)) * 256 + ks * 32 + (c & 3) * 8,
              (char*)Bl + (j * 4 + w) * 1024);
    }
    __syncthreads();
    f16x8 af[4], bf[4];
#pragma unroll
    for (int i = 0; i < 4; ++i)
      af[i] = *(const f16x8*)((const char*)Al + (wm * 64 + i * 16 + lr) * 64 + lg * 16);
#pragma unroll
    for (int i = 0; i < 4; ++i)
      bf[i] = *(const f16x8*)((const char*)Bl + (wn * 64 + i * 16 + lr) * 64 + lg * 16);
#pragma unroll
    for (int mi = 0; mi < 4; ++mi)
#pragma unroll
      for (int ni = 0; ni < 4; ++ni)
        acc[mi][ni] = __builtin_amdgcn_mfma_f32_16x16x32_f16(af[mi], bf[ni], acc[mi][ni], 0, 0, 0);
  }
  const int proj = nt >> 1;
  const float* bias = proj == 0 ? bq : (proj == 1 ? bk : bv);
  const float qsc = 0.25504182524668425f; // log2(e)/sqrt(32)
#pragma unroll
  for (int mi = 0; mi < 4; ++mi) {
#pragma unroll
    for (int ni = 0; ni < 4; ++ni) {
      int n = nbase + wn * 64 + ni * 16 + lr;
      float bb = bias[n & 255];
#pragma unroll
      for (int r = 0; r < 4; ++r) {
        int m = mbase + wm * 64 + mi * 16 + lg * 4 + r;
        float val = acc[mi][ni][r] + bb;
        if (proj == 0) val *= qsc;
        f16 hv = (f16)val;
        int b = m >> 10, s = m & 1023;
        int hh = (n >> 5) & 7, dd = n & 31;
        int bh = b * 8 + hh;
        if (proj == 0)      qh[((size_t)bh * 1024 + s) * 32 + dd] = hv;
        else if (proj == 1) kh[((size_t)bh * 1024 + s) * 32 + dd] = hv;
        else                vth[((size_t)bh * 32 + dd) * 1024 + s] = hv;
      }
    }
  }
}

// Flash attention v5: KVBLK=128, per-row max, XCD swizzle, setprio,
// FULL K+V double-buffer + robust 12-op vmcnt ledger + lgkmcnt drain before bar1
// (fixes v3/v4 races: load-reorder vmcnt miscount + pending-ds_read vs LDS-write).
__global__ __launch_bounds__(256, 3) void attn_kernel(
    const f16* __restrict__ qh, const f16* __restrict__ kh, const f16* __restrict__ vth,
    const unsigned* __restrict__ pmx, f16* __restrict__ attnh) {
  __shared__ __align__(16) f16 Kl[2][128 * 32];   // 2 x 8KB
  __shared__ __align__(16) f16 Vtl[2][32 * 128];  // 2 x 8KB
  __shared__ __align__(16) f16 Pl[4][16 * 128];   // 4 x 4KB per-wave P
  const int tid = threadIdx.x;
  const int w = tid >> 6, l = tid & 63;
  // XCD swizzle: all 16 q-tiles of one bh land on one XCD (blockIdx%8 = XCD).
  const int dsp = blockIdx.x;
  const int slot = dsp >> 3;
  const int bh = (slot >> 4) * 8 + (dsp & 7);
  const int qt = slot & 15;
  const int qbase = qt * 64;
  const int lg = l >> 4, lr = l & 15;
  const int q = qbase + w * 16 + lr;   // lane's q-row (col side of swapped QK)

  f16x8 qf = *(const f16x8*)(qh + ((size_t)bh * 1024 + q) * 32 + lg * 8);
  const unsigned* mrow = pmx + (size_t)q * 512;

  float mrun = -1e30f;                 // per-ROW running max (uniform across lg lanes)
  f32x4 oacc[2] = {};
  f32x4 lacc = {};
  const f32x4 zero = {};
  f16x8 ones;
#pragma unroll
  for (int i = 0; i < 8; ++i) ones[i] = (f16)1.0f;

  // staging sources
  const f16* kg = kh + ((size_t)bh * 1024 + (tid >> 2)) * 32 + (tid & 3) * 8;
  const int dv0 = tid >> 4, cb = tid & 15;
  const f16* vg0 = vth + ((size_t)bh * 32 + dv0) * 1024 + (size_t)((cb ^ (dv0 & 7)) * 8);
  char* kl0 = (char*)Kl[0];
  char* kl1 = (char*)Kl[1];
  char* vl0 = (char*)Vtl[0];
  char* vl1 = (char*)Vtl[1];
  char* pbuf = (char*)Pl[w];

  // prologue: tile 0 = mask(0) x8 + K(0) x2 + V(0) x2  (12 vmem ops)
  uint2 mca[8], mcb[8];
#pragma unroll
  for (int k = 0; k < 8; ++k) mca[k] = *(const uint2*)(mrow + k * 8 + lg * 2);
  gload16(kg, kl0 + tid * 16);
  gload16(kg + 2048, kl0 + tid * 16 + 4096);
  gload16(vg0, vl0 + tid * 16);
  gload16(vg0 + 16 * 1024, vl0 + tid * 16 + 4096);

  // Per iter T: issue tile T+1's 12 ops; vmcnt(12) leaves exactly those 12
  // (any intra-bracket order) => tile T's staging (issued in iter T-1) drained.
  // lgkmcnt(0) before bar1 => no wave crosses with pending ds_reads of the
  // buffers tile T+1 will overwrite.
#define DOTILE(T, KCUR, KNXT, VCUR, VNXT, MC, MN)                                   \
  {                                                                                 \
    asm volatile("s_waitcnt lgkmcnt(0)" ::: "memory");                              \
    __builtin_amdgcn_s_barrier();            /* all waves done with tile T-1 */     \
    if ((T) < 7) {                                                                  \
      _Pragma("unroll") for (int k = 0; k < 8; ++k)                                 \
          MN[k] = *(const uint2*)(mrow + ((T) + 1) * 64 + k * 8 + lg * 2);          \
      gload16(kg + ((T) + 1) * 4096, (KNXT) + tid * 16);                            \
      gload16(kg + ((T) + 1) * 4096 + 2048, (KNXT) + tid * 16 + 4096);              \
      gload16(vg0 + ((T) + 1) * 128, (VNXT) + tid * 16);                            \
      gload16(vg0 + 16 * 1024 + ((T) + 1) * 128, (VNXT) + tid * 16 + 4096);         \
      asm volatile("s_waitcnt vmcnt(12)" ::: "memory");  /* tile T arrived */       \
    } else {                                                                        \
      asm volatile("s_waitcnt vmcnt(0)" ::: "memory");                              \
    }                                                                               \
    __builtin_amdgcn_s_barrier();            /* every wave's tile-T staging in */   \
    f32x4 sc[8];                                                                    \
    __builtin_amdgcn_s_setprio(1);                                                  \
    _Pragma("unroll") for (int kt = 0; kt < 8; ++kt) {                              \
      f16x8 kf = *(const f16x8*)((KCUR) + (kt * 16 + lr) * 64 + lg * 16);           \
      sc[kt] = __builtin_amdgcn_mfma_f32_16x16x32_f16(kf, qf, zero, 0, 0, 0);       \
    }                                                                               \
    __builtin_amdgcn_s_setprio(0);                                                  \
    float m0 = fmaxf(fmaxf(sc[0][0], sc[0][1]), fmaxf(sc[0][2], sc[0][3]));         \
    float m1 = fmaxf(fmaxf(sc[1][0], sc[1][1]), fmaxf(sc[1][2], sc[1][3]));         \
    float m2 = fmaxf(fmaxf(sc[2][0], sc[2][1]), fmaxf(sc[2][2], sc[2][3]));         \
    float m3 = fmaxf(fmaxf(sc[3][0], sc[3][1]), fmaxf(sc[3][2], sc[3][3]));         \
    float m4 = fmaxf(fmaxf(sc[4][0], sc[4][1]), fmaxf(sc[4][2], sc[4][3]));         \
    float m5 = fmaxf(fmaxf(sc[5][0], sc[5][1]), fmaxf(sc[5][2], sc[5][3]));         \
    float m6 = fmaxf(fmaxf(sc[6][0], sc[6][1]), fmaxf(sc[6][2], sc[6][3]));         \
    float m7 = fmaxf(fmaxf(sc[7][0], sc[7][1]), fmaxf(sc[7][2], sc[7][3]));         \
    float pmax = fmaxf(fmaxf(fmaxf(m0, m1), fmaxf(m2, m3)),                         \
                       fmaxf(fmaxf(m4, m5), fmaxf(m6, m7)));                        \
    pmax = fmaxf(pmax, __shfl_xor(pmax, 16));                                       \
    pmax = fmaxf(pmax, __shfl_xor(pmax, 32));  /* per-ROW max */                    \
    if (__any(pmax > mrun + 8.0f)) {                                                \
      float mnew = fmaxf(mrun, pmax);          /* per-row */                        \
      float alpha = ex2(mrun - mnew);                                               \
      mrun = mnew;                                                                  \
      _Pragma("unroll") for (int r = 0; r < 4; ++r) {                               \
        float ar = __shfl(alpha, (l & 48) | (lg * 4 + r), 64);                      \
        oacc[0][r] *= ar; oacc[1][r] *= ar; lacc[r] *= ar;                          \
      }                                                                             \
    }                                                                               \
    _Pragma("unroll") for (int kt = 0; kt < 8; ++kt) {                              \
      float p0 = ex2(sc[kt][0] - mrun), p1 = ex2(sc[kt][1] - mrun);                 \
      float p2 = ex2(sc[kt][2] - mrun), p3 = ex2(sc[kt][3] - mrun);                 \
      unsigned lo = pkmul(pkrtz(p0, p1), MC[kt].x);                                 \
      unsigned hi = pkmul(pkrtz(p2, p3), MC[kt].y);                                 \
      *(uint64_t*)(pbuf + lr * 256 + ((kt * 32 + lg * 8) ^ ((lr & 7) << 4))) =      \
          (uint64_t)lo | ((uint64_t)hi << 32);                                      \
    }                                                                               \
    __builtin_amdgcn_s_setprio(1);                                                  \
    _Pragma("unroll") for (int ss = 0; ss < 4; ++ss) {                              \
      f16x8 pa = *(const f16x8*)(pbuf + lr * 256 +                                  \
                                 ((ss * 64 + lg * 16) ^ ((lr & 7) << 4)));          \
      lacc = __builtin_amdgcn_mfma_f32_16x16x32_f16(pa, ones, lacc, 0, 0, 0);       \
      _Pragma("unroll") for (int dt = 0; dt < 2; ++dt) {                            \
        f16x8 vf = *(const f16x8*)((VCUR) + (dt * 16 + lr) * 256 +                  \
                                   ((ss * 64 + lg * 16) ^ ((lr & 7) << 4)));        \
        oacc[dt] = __builtin_amdgcn_mfma_f32_16x16x32_f16(pa, vf, oacc[dt], 0, 0, 0); \
      }                                                                             \
    }                                                                               \
    __builtin_amdgcn_s_setprio(0);                                                  \
  }

  DOTILE(0, kl0, kl1, vl0, vl1, mca, mcb)
  DOTILE(1, kl1, kl0, vl1, vl0, mcb, mca)
  DOTILE(2, kl0, kl1, vl0, vl1, mca, mcb)
  DOTILE(3, kl1, kl0, vl1, vl0, mcb, mca)
  DOTILE(4, kl0, kl1, vl0, vl1, mca, mcb)
  DOTILE(5, kl1, kl0, vl1, vl0, mcb, mca)
  DOTILE(6, kl0, kl1, vl0, vl1, mca, mcb)
  DOTILE(7, kl1, kl0, vl1, vl0, mcb, mca)
#undef DOTILE

  const int b = bh >> 3, hh = bh & 7;
#pragma unroll
  for (int r = 0; r < 4; ++r) {
    float inv = 1.0f / lacc[r];
    int qrow = qbase + w * 16 + lg * 4 + r;
    size_t rowoff = ((size_t)b * 1024 + qrow) * 256 + hh * 32;
    attnh[rowoff + lr]      = (f16)(oacc[0][r] * inv);
    attnh[rowoff + 16 + lr] = (f16)(oacc[1][r] * inv);
  }
}

__global__ __launch_bounds__(256) void out_gemm_kernel(
    const f16* __restrict__ ah, const f16* __restrict__ wh,
    const float* __restrict__ bo, float* __restrict__ out) {
  __shared__ __align__(16) f16 Al[128 * 32];
  __shared__ __align__(16) f16 Bl[128 * 32];
  const int tid = threadIdx.x;
  const int w = tid >> 6, l = tid & 63;
  const int mt = blockIdx.x >> 1, nt = blockIdx.x & 1;
  const int mbase = mt * 128, nbase = nt * 128;
  const int wm = w >> 1, wn = w & 1;
  const int lg = l >> 4, lr = l & 15;
  f32x4 acc[4][4] = {};
  for (int ks = 0; ks < 8; ++ks) {
    __syncthreads();
#pragma unroll
    for (int j = 0; j < 2; ++j) {
      int c = (j * 4 + w) * 64 + l;
      gload16(ah + (size_t)(mbase + (c >> 2)) * 256 + ks * 32 + (c & 3) * 8,
              (char*)Al + (j * 4 + w) * 1024);
      gload16(wh + (size_t)(nbase + (c >> 2)) * 256 + ks * 32 + (c & 3) * 8,
              (char*)Bl + (j * 4 + w) * 1024);
    }
    __syncthreads();
    f16x8 af[4], bf[4];
#pragma unroll
    for (int i = 0; i < 4; ++i)
      af[i] = *(const f16x8*)((const char*)Al + (wm * 64 + i * 16 + lr) * 64 + lg * 16);
#pragma unroll
    for (int i = 0; i < 4; ++i)
      bf[i] = *(const f16x8*)((const char*)Bl + (wn * 64 + i * 16 + lr) * 64 + lg * 16);
#pragma unroll
    for (int mi = 0; mi < 4; ++mi)
#pragma unroll
      for (int ni = 0; ni < 4; ++ni)
        acc[mi][ni] = __builtin_amdgcn_mfma_f32_16x16x32_f16(af[mi], bf[ni], acc[mi][ni], 0, 0, 0);
  }
#pragma unroll
  for (int mi = 0; mi < 4; ++mi) {
#pragma unroll
    for (int ni = 0; ni < 4; ++ni) {
      int n = nbase + wn * 64 + ni * 16 + lr;
      float bb = bo[n];
#pragma unroll
      for (int r = 0; r < 4; ++r) {
        int m = mbase + wm * 64 + mi * 16 + lg * 4 + r;
        out[(size_t)m * 256 + n] = acc[mi][ni][r] + bb;
      }
    }
  }
}

extern "C" void kernel_launch(void* const* d_in, const int* in_sizes, int n_in,
                              void* d_out, int out_size, void* d_ws, size_t ws_size,
                              hipStream_t stream) {
  const float* x  = (const float*)d_in[0];
  const int* mask = (const int*)d_in[1];
  const float* Wq = (const float*)d_in[2];
  const float* bq = (const float*)d_in[3];
  const float* Wk = (const float*)d_in[4];
  const float* bk = (const float*)d_in[5];
  const float* Wv = (const float*)d_in[6];
  const float* bv = (const float*)d_in[7];
  const float* Wo = (const float*)d_in[8];
  const float* bo = (const float*)d_in[9];
  float* out = (float*)d_out;
  char* ws = (char*)d_ws;

  f16* xh    = (f16*)(ws);                 // 16 MB (aliased by attnh after QKV GEMM)
  f16* attnh = (f16*)(ws);
  f16* qh    = (f16*)(ws + 16777216);
  f16* kh    = (f16*)(ws + 33554432);
  f16* vth   = (f16*)(ws + 50331648);      // V transposed [bh][32][1024]
  f16* wqkvh = (f16*)(ws + 67108864);      // [768][256] then Wo [256][256] contiguous
  f16* woh   = (f16*)(ws + 67502080);
  unsigned* pmx = (unsigned*)(ws + 67633152); // [1024][512] f16-pair mask table (2 MB)

  prep_kernel<<<10496, 256, 0, stream>>>(x, Wq, Wk, Wv, Wo, mask, xh, wqkvh, pmx);
  qkv_gemm_kernel<<<1536, 256, 0, stream>>>(xh, wqkvh, bq, bk, bv, qh, kh, vth);
  attn_kernel<<<4096, 256, 0, stream>>>(qh, kh, vth, pmx, attnh);
  out_gemm_kernel<<<512, 256, 0, stream>>>(attnh, woh, bo, out);
}